// Round 1
// baseline (609.456 us; speedup 1.0000x reference)
//
#include <hip/hip_runtime.h>
#include <math.h>

#define BB 16
#define DD 1024
#define TT 4096
#define CD 8
#define CS 1024

// d_out layout (float elements):
//   out      [B][D][T]   @ 0          (67108864)
//   commit   [B]         @ 67108864
//   code     [B]         @ 67108880
//   indices  [B][T]      @ 67108896   (65536, written as float)
//   z_e      [B][CD][T]  @ 67174432   (524288)
#define OFF_LOSS_C 67108864
#define OFF_LOSS_B 67108880
#define OFF_IDX    67108896
#define OFF_ZE     67174432

// ws layout (float elements):
//   w_in_T [D][CD] @ 0
//   w_out  [D][CD] @ 8192
//   cbn    [CS][CD] @ 16384
//   cs     [CS] (double) @ 24576 (occupies 2048 float slots)
#define WS_WIN  0
#define WS_WOUT 8192
#define WS_CBN  16384
#define WS_CS   24576

__global__ __launch_bounds__(256) void prep_kernel(
    const float* __restrict__ in_v,   // [CD][D]
    const float* __restrict__ in_g,   // [CD]
    const float* __restrict__ out_v,  // [D][CD]
    const float* __restrict__ out_g,  // [D]
    const float* __restrict__ cb,     // [CS][CD]
    float* __restrict__ ws)
{
    __shared__ float red[256];
    __shared__ float s_in[CD];
    int tid = threadIdx.x;

    // in_proj row scales: g[o] / ||v[o,:]||  (norm over D)
    for (int o = 0; o < CD; ++o) {
        float p = 0.f;
        for (int k = tid; k < DD; k += 256) { float v = in_v[o*DD + k]; p += v*v; }
        red[tid] = p; __syncthreads();
        for (int s = 128; s > 0; s >>= 1) { if (tid < s) red[tid] += red[tid+s]; __syncthreads(); }
        if (tid == 0) s_in[o] = in_g[o] / sqrtf(red[0]);
        __syncthreads();
    }
    // w_in transposed: ws[d*8+o] = v[o][d] * s_in[o]
    for (int i = tid; i < DD*CD; i += 256) {
        int d = i >> 3, o = i & 7;
        ws[WS_WIN + i] = in_v[o*DD + d] * s_in[o];
    }
    // w_out: ws[8192 + d*8+c] = out_v[d][c] * g[d]/||row||
    for (int d = tid; d < DD; d += 256) {
        float v[CD]; float ssq = 0.f;
        #pragma unroll
        for (int c = 0; c < CD; ++c) { v[c] = out_v[d*CD + c]; ssq += v[c]*v[c]; }
        float s = out_g[d] / sqrtf(ssq);
        #pragma unroll
        for (int c = 0; c < CD; ++c) ws[WS_WOUT + d*CD + c] = v[c]*s;
    }
    // normalized codebook + fp64 sumsq of the fp32-normalized rows
    double* cs = (double*)(ws + WS_CS);
    for (int c = tid; c < CS; c += 256) {
        float v[CD]; float ssq = 0.f;
        #pragma unroll
        for (int j = 0; j < CD; ++j) { v[j] = cb[c*CD + j]; ssq += v[j]*v[j]; }
        float n = fmaxf(sqrtf(ssq), 1e-12f);
        double sq = 0.0;
        #pragma unroll
        for (int j = 0; j < CD; ++j) {
            float e = v[j] / n;
            ws[WS_CBN + c*CD + j] = e;
            sq += (double)e * (double)e;
        }
        cs[c] = sq;
    }
}

__global__ __launch_bounds__(256) void vq_main_kernel(
    const float* __restrict__ z,     // [B][D][T]
    const float* __restrict__ in_b,  // [CD]
    const float* __restrict__ cb,    // [CS][CD] raw
    const float* __restrict__ ws,
    float* __restrict__ outb)
{
    __shared__ float4 cbn_s[CS*2];   // 32 KB: code c -> cbn_s[2c], cbn_s[2c+1]
    __shared__ double cs_s[CS];      // 8 KB
    __shared__ float red[4];

    int tid = threadIdx.x;
    int b = blockIdx.y;
    int t = blockIdx.x * 256 + tid;

    // stage normalized codebook + sumsq into LDS
    {
        const float4* src = (const float4*)(ws + WS_CBN);
        for (int i = tid; i < CS*2; i += 256) cbn_s[i] = src[i];
        const double* csg = (const double*)(ws + WS_CS);
        for (int i = tid; i < CS; i += 256) cs_s[i] = csg[i];
    }
    __syncthreads();

    // phase A: z_e[o] = b[o] + sum_d w_in[o][d]*z[b][d][t]
    float acc[CD];
    #pragma unroll
    for (int o = 0; o < CD; ++o) acc[o] = in_b[o];
    const float* zp = z + (size_t)b * DD * TT + t;
    const float* w = ws + WS_WIN;     // [d][o], wave-uniform reads -> scalar loads
    #pragma unroll 8
    for (int d = 0; d < DD; ++d) {
        float zv = zp[(size_t)d * TT];
        #pragma unroll
        for (int o = 0; o < CD; ++o) acc[o] = fmaf(w[d*CD + o], zv, acc[o]);
    }

    // write z_e (coalesced per o)
    #pragma unroll
    for (int o = 0; o < CD; ++o)
        outb[OFF_ZE + ((size_t)(b*CD + o)) * TT + t] = acc[o];

    // normalize e in fp32 (matches reference _l2norm), promote to fp64
    float ssq = 0.f;
    #pragma unroll
    for (int o = 0; o < CD; ++o) ssq += acc[o]*acc[o];
    float nrm = fmaxf(sqrtf(ssq), 1e-12f);
    double en[CD];
    #pragma unroll
    for (int o = 0; o < CD; ++o) en[o] = (double)(acc[o] / nrm);

    // argmax_c 2*dot(e_n, c_n) - |c_n|^2   (fp64 scoring; strict > = first-occurrence ties)
    double best = -1.0e300; int bidx = 0;
    for (int c = 0; c < CS; ++c) {
        float4 r0 = cbn_s[2*c], r1 = cbn_s[2*c+1];
        double dot = 0.0;
        dot = fma((double)r0.x, en[0], dot);
        dot = fma((double)r0.y, en[1], dot);
        dot = fma((double)r0.z, en[2], dot);
        dot = fma((double)r0.w, en[3], dot);
        dot = fma((double)r1.x, en[4], dot);
        dot = fma((double)r1.y, en[5], dot);
        dot = fma((double)r1.z, en[6], dot);
        dot = fma((double)r1.w, en[7], dot);
        double score = 2.0*dot - cs_s[c];
        if (score > best) { best = score; bidx = c; }
    }
    outb[OFF_IDX + b*TT + t] = (float)bidx;

    // loss: sum (z_e - z_q)^2 over CD, raw codebook gather (L1/L2-resident)
    float l = 0.f;
    const float4* qr = (const float4*)(cb + bidx*CD);
    float4 q0 = qr[0], q1 = qr[1];
    {
        float dlt;
        dlt = acc[0]-q0.x; l = fmaf(dlt,dlt,l);
        dlt = acc[1]-q0.y; l = fmaf(dlt,dlt,l);
        dlt = acc[2]-q0.z; l = fmaf(dlt,dlt,l);
        dlt = acc[3]-q0.w; l = fmaf(dlt,dlt,l);
        dlt = acc[4]-q1.x; l = fmaf(dlt,dlt,l);
        dlt = acc[5]-q1.y; l = fmaf(dlt,dlt,l);
        dlt = acc[6]-q1.z; l = fmaf(dlt,dlt,l);
        dlt = acc[7]-q1.w; l = fmaf(dlt,dlt,l);
    }
    #pragma unroll
    for (int off = 32; off > 0; off >>= 1) l += __shfl_down(l, off, 64);
    if ((tid & 63) == 0) red[tid >> 6] = l;
    __syncthreads();
    if (tid == 0) {
        float s = ((red[0]+red[1]) + (red[2]+red[3])) * (1.0f/(CD*TT));
        atomicAdd(outb + OFF_LOSS_C + b, s);
        atomicAdd(outb + OFF_LOSS_B + b, s);  // identical values
    }
}

__global__ __launch_bounds__(256) void out_proj_kernel(
    const float* __restrict__ cb,    // raw codebook
    const float* __restrict__ out_b, // [D]
    const float* __restrict__ ws,
    float* __restrict__ outb)
{
    __shared__ float4 wout_s[DD*2];                 // 32 KB
    __shared__ __align__(16) float zq_s[CD][128];   // 4 KB
    __shared__ float bias_s[DD];                    // 4 KB

    int tid = threadIdx.x;
    int b = blockIdx.y;
    int t0 = blockIdx.x * 128;

    const float4* wsrc = (const float4*)(ws + WS_WOUT);
    for (int i = tid; i < DD*2; i += 256) wout_s[i] = wsrc[i];
    for (int i = tid; i < DD; i += 256) bias_s[i] = out_b[i];
    if (tid < 128) {
        int idx = (int)outb[OFF_IDX + b*TT + t0 + tid];
        const float4* cr = (const float4*)(cb + idx*CD);
        float4 q0 = cr[0], q1 = cr[1];
        zq_s[0][tid] = q0.x; zq_s[1][tid] = q0.y; zq_s[2][tid] = q0.z; zq_s[3][tid] = q0.w;
        zq_s[4][tid] = q1.x; zq_s[5][tid] = q1.y; zq_s[6][tid] = q1.z; zq_s[7][tid] = q1.w;
    }
    __syncthreads();

    int tq = tid & 31;     // 32 groups x float4 = 128 t
    int dg = tid >> 5;     // 0..7
    float4 qv[CD];
    #pragma unroll
    for (int c = 0; c < CD; ++c) qv[c] = *(const float4*)&zq_s[c][tq*4];

    size_t obase = (size_t)b * DD * TT + t0 + tq*4;
    #pragma unroll 4
    for (int i = 0; i < 128; ++i) {
        int d = i*8 + dg;
        float4 w0 = wout_s[2*d], w1 = wout_s[2*d+1];
        float bb = bias_s[d];
        float4 r = make_float4(bb, bb, bb, bb);
        r.x = fmaf(w0.x, qv[0].x, r.x); r.y = fmaf(w0.x, qv[0].y, r.y); r.z = fmaf(w0.x, qv[0].z, r.z); r.w = fmaf(w0.x, qv[0].w, r.w);
        r.x = fmaf(w0.y, qv[1].x, r.x); r.y = fmaf(w0.y, qv[1].y, r.y); r.z = fmaf(w0.y, qv[1].z, r.z); r.w = fmaf(w0.y, qv[1].w, r.w);
        r.x = fmaf(w0.z, qv[2].x, r.x); r.y = fmaf(w0.z, qv[2].y, r.y); r.z = fmaf(w0.z, qv[2].z, r.z); r.w = fmaf(w0.z, qv[2].w, r.w);
        r.x = fmaf(w0.w, qv[3].x, r.x); r.y = fmaf(w0.w, qv[3].y, r.y); r.z = fmaf(w0.w, qv[3].z, r.z); r.w = fmaf(w0.w, qv[3].w, r.w);
        r.x = fmaf(w1.x, qv[4].x, r.x); r.y = fmaf(w1.x, qv[4].y, r.y); r.z = fmaf(w1.x, qv[4].z, r.z); r.w = fmaf(w1.x, qv[4].w, r.w);
        r.x = fmaf(w1.y, qv[5].x, r.x); r.y = fmaf(w1.y, qv[5].y, r.y); r.z = fmaf(w1.y, qv[5].z, r.z); r.w = fmaf(w1.y, qv[5].w, r.w);
        r.x = fmaf(w1.z, qv[6].x, r.x); r.y = fmaf(w1.z, qv[6].y, r.y); r.z = fmaf(w1.z, qv[6].z, r.z); r.w = fmaf(w1.z, qv[6].w, r.w);
        r.x = fmaf(w1.w, qv[7].x, r.x); r.y = fmaf(w1.w, qv[7].y, r.y); r.z = fmaf(w1.w, qv[7].w, r.w); r.w = fmaf(w1.w, qv[7].w, r.w);
        *(float4*)(outb + obase + (size_t)d * TT) = r;
    }
}

extern "C" void kernel_launch(void* const* d_in, const int* in_sizes, int n_in,
                              void* d_out, int out_size, void* d_ws, size_t ws_size,
                              hipStream_t stream) {
    const float* z     = (const float*)d_in[0];
    const float* in_v  = (const float*)d_in[1];
    const float* in_g  = (const float*)d_in[2];
    const float* in_b  = (const float*)d_in[3];
    const float* out_v = (const float*)d_in[4];
    const float* out_g = (const float*)d_in[5];
    const float* out_b = (const float*)d_in[6];
    const float* cb    = (const float*)d_in[7];
    float* ws  = (float*)d_ws;
    float* out = (float*)d_out;

    // zero the 32 loss accumulators (harness poisons d_out with 0xAA)
    hipMemsetAsync(out + OFF_LOSS_C, 0, 32 * sizeof(float), stream);

    prep_kernel<<<1, 256, 0, stream>>>(in_v, in_g, out_v, out_g, cb, ws);
    vq_main_kernel<<<dim3(TT/256, BB), 256, 0, stream>>>(z, in_b, cb, ws, out);
    out_proj_kernel<<<dim3(TT/128, BB), 256, 0, stream>>>(cb, out_b, ws, out);
}

// Round 2
// 586.983 us; speedup vs baseline: 1.0383x; 1.0383x over previous
//
#include <hip/hip_runtime.h>
#include <math.h>

#define BB 16
#define DD 1024
#define TT 4096
#define CD 8
#define CS 1024

// d_out layout (float elements):
//   out      [B][D][T]   @ 0          (67108864)
//   commit   [B]         @ 67108864
//   code     [B]         @ 67108880
//   indices  [B][T]      @ 67108896   (65536, written as float)
//   z_e      [B][CD][T]  @ 67174432   (524288)
#define OFF_LOSS_C 67108864
#define OFF_LOSS_B 67108880
#define OFF_IDX    67108896
#define OFF_ZE     67174432

// ws layout (float elements):
//   w_in_T [D][CD] @ 0       (transposed: ws[d*8+o])
//   w_out  [D][CD] @ 8192
//   cbn    [CS][CD] @ 16384  (fp32 L2-normalized codebook rows)
//   csh    [CS] (double) @ 24576 : 0.5*|c_n|^2 in fp64
#define WS_WIN  0
#define WS_WOUT 8192
#define WS_CBN  16384
#define WS_CS   24576

// ---------------- prep: 16 blocks, fully parallel ----------------
__global__ __launch_bounds__(256) void prep_kernel(
    const float* __restrict__ in_v,   // [CD][D]
    const float* __restrict__ in_g,   // [CD]
    const float* __restrict__ out_v,  // [D][CD]
    const float* __restrict__ out_g,  // [D]
    const float* __restrict__ cb,     // [CS][CD]
    float* __restrict__ ws)
{
    int bid = blockIdx.x, tid = threadIdx.x;
    if (bid < 8) {
        // one block per in_proj output row o
        __shared__ float red[256];
        __shared__ float ssc;
        int o = bid;
        float p = 0.f;
        for (int k = tid; k < DD; k += 256) { float v = in_v[o*DD + k]; p += v*v; }
        red[tid] = p; __syncthreads();
        for (int s = 128; s > 0; s >>= 1) { if (tid < s) red[tid] += red[tid+s]; __syncthreads(); }
        if (tid == 0) ssc = in_g[o] / sqrtf(red[0]);
        __syncthreads();
        float scale = ssc;
        for (int d = tid; d < DD; d += 256)
            ws[WS_WIN + d*CD + o] = in_v[o*DD + d] * scale;
    } else if (bid < 12) {
        // w_out rows, 256 d per block
        int d = (bid - 8) * 256 + tid;
        float v[CD]; float ssq = 0.f;
        #pragma unroll
        for (int c = 0; c < CD; ++c) { v[c] = out_v[d*CD + c]; ssq += v[c]*v[c]; }
        float s = out_g[d] / sqrtf(ssq);
        #pragma unroll
        for (int c = 0; c < CD; ++c) ws[WS_WOUT + d*CD + c] = v[c]*s;
    } else {
        // codebook rows, 256 c per block
        int c = (bid - 12) * 256 + tid;
        double* csh = (double*)(ws + WS_CS);
        float v[CD]; float ssq = 0.f;
        #pragma unroll
        for (int j = 0; j < CD; ++j) { v[j] = cb[c*CD + j]; ssq += v[j]*v[j]; }
        float n = fmaxf(sqrtf(ssq), 1e-12f);
        double sq = 0.0;
        #pragma unroll
        for (int j = 0; j < CD; ++j) {
            float e = v[j] / n;
            ws[WS_CBN + c*CD + j] = e;
            sq = fma((double)e, (double)e, sq);
        }
        csh[c] = 0.5 * sq;
    }
}

// ---------------- vq: 64 t per block, d-reduction + argmax split over 4 waves ----------------
__global__ __launch_bounds__(256) void vq_kernel(
    const float* __restrict__ z,     // [B][D][T]
    const float* __restrict__ in_b,  // [CD]
    const float* __restrict__ cb,    // [CS][CD] raw
    const float* __restrict__ ws,
    float* __restrict__ outb)
{
    __shared__ float  zpart[4][CD][64];   // 8 KB
    __shared__ float  ze_s[CD][64];       // 2 KB
    __shared__ float  nrm_s[64];
    __shared__ double best_s[4][64];      // 2 KB
    __shared__ int    bidx_s[4][64];      // 1 KB

    int tid = threadIdx.x;
    int b   = blockIdx.y;
    int t0  = blockIdx.x * 64;
    int tl  = tid & 63;
    int wv  = __builtin_amdgcn_readfirstlane(tid >> 6);  // wave id 0..3, provably uniform

    // ---- phase A: partial z_e over 256 d per wave ----
    const float* zp = z + ((size_t)(b*DD + wv*256)) * TT + t0 + tl;
    const float* w  = ws + WS_WIN + wv*256*CD;           // uniform -> scalar loads
    float acc[CD];
    #pragma unroll
    for (int o = 0; o < CD; ++o) acc[o] = 0.f;
    #pragma unroll 8
    for (int j = 0; j < 256; ++j) {
        float zv = zp[(size_t)j * TT];
        #pragma unroll
        for (int o = 0; o < CD; ++o) acc[o] = fmaf(w[j*CD + o], zv, acc[o]);
    }
    #pragma unroll
    for (int o = 0; o < CD; ++o) zpart[wv][o][tl] = acc[o];
    __syncthreads();

    // combine 4 partials + bias; write z_e (each thread handles 2 (o,t) pairs)
    #pragma unroll
    for (int p = tid; p < 512; p += 256) {
        int o = p >> 6, t = p & 63;
        float v = in_b[o] + ((zpart[0][o][t] + zpart[1][o][t]) +
                             (zpart[2][o][t] + zpart[3][o][t]));
        ze_s[o][t] = v;
        outb[OFF_ZE + ((size_t)(b*CD + o)) * TT + t0 + t] = v;
    }
    __syncthreads();
    if (tid < 64) {
        float ssq = 0.f;
        #pragma unroll
        for (int o = 0; o < CD; ++o) { float v = ze_s[o][tid]; ssq = fmaf(v, v, ssq); }
        nrm_s[tid] = fmaxf(sqrtf(ssq), 1e-12f);
    }
    __syncthreads();

    // ---- phase B: argmax over 256 codes per wave (fp64 scoring) ----
    {
        int t = tl;
        float nr = nrm_s[t];
        double en[CD];
        #pragma unroll
        for (int o = 0; o < CD; ++o) en[o] = (double)(ze_s[o][t] / nr);
        const float*  cbn = ws + WS_CBN;
        const double* csh = (const double*)(ws + WS_CS);
        int c0 = wv * 256;
        double best = -1.0e300; int bi = c0;
        for (int c = c0; c < c0 + 256; ++c) {
            float cr[CD];
            *(float4*)&cr[0] = *(const float4*)(cbn + c*CD);
            *(float4*)&cr[4] = *(const float4*)(cbn + c*CD + 4);
            double dot = 0.0;
            #pragma unroll
            for (int o = 0; o < CD; ++o) dot = fma((double)cr[o], en[o], dot);
            double score = dot - csh[c];   // monotone in 2*dot - |c|^2
            if (score > best) { best = score; bi = c; }
        }
        best_s[wv][t] = best; bidx_s[wv][t] = bi;
    }
    __syncthreads();

    // ---- combine chunks, index write, losses ----
    if (tid < 64) {
        int t = tid;
        double best = best_s[0][t]; int bi = bidx_s[0][t];
        #pragma unroll
        for (int k = 1; k < 4; ++k) {
            if (best_s[k][t] > best) { best = best_s[k][t]; bi = bidx_s[k][t]; }
        }
        outb[OFF_IDX + b*TT + t0 + t] = (float)bi;

        float q[CD];
        *(float4*)&q[0] = *(const float4*)(cb + bi*CD);
        *(float4*)&q[4] = *(const float4*)(cb + bi*CD + 4);
        float l = 0.f;
        #pragma unroll
        for (int o = 0; o < CD; ++o) { float d = ze_s[o][t] - q[o]; l = fmaf(d, d, l); }
        #pragma unroll
        for (int off = 32; off > 0; off >>= 1) l += __shfl_down(l, off, 64);
        if (tid == 0) {
            float s = l * (1.0f / (CD * TT));
            atomicAdd(outb + OFF_LOSS_C + b, s);
            atomicAdd(outb + OFF_LOSS_B + b, s);
        }
    }
}

// ---------------- out_proj: 64 t per block, 1024 blocks ----------------
__global__ __launch_bounds__(256) void out_proj_kernel(
    const float* __restrict__ cb,    // raw codebook
    const float* __restrict__ out_b, // [D]
    const float* __restrict__ ws,
    float* __restrict__ outb)
{
    __shared__ __align__(16) float zq_s[CD][64];   // 2 KB

    int tid = threadIdx.x;
    int b   = blockIdx.y;
    int t0  = blockIdx.x * 64;

    if (tid < 64) {
        int bi = (int)outb[OFF_IDX + b*TT + t0 + tid];
        const float4* cr = (const float4*)(cb + bi*CD);
        float4 q0 = cr[0], q1 = cr[1];
        zq_s[0][tid] = q0.x; zq_s[1][tid] = q0.y; zq_s[2][tid] = q0.z; zq_s[3][tid] = q0.w;
        zq_s[4][tid] = q1.x; zq_s[5][tid] = q1.y; zq_s[6][tid] = q1.z; zq_s[7][tid] = q1.w;
    }
    __syncthreads();

    int tq = tid & 15;     // 16 groups x float4 = 64 t
    int dg = tid >> 4;     // 0..15
    float4 qv[CD];
    #pragma unroll
    for (int o = 0; o < CD; ++o) qv[o] = *(const float4*)&zq_s[o][tq*4];

    size_t obase = (size_t)b * DD * TT + t0 + tq*4;
    const float4* wv4 = (const float4*)(ws + WS_WOUT);
    #pragma unroll 4
    for (int i = 0; i < 64; ++i) {
        int d = i*16 + dg;
        float wr[CD];
        *(float4*)&wr[0] = wv4[2*d];
        *(float4*)&wr[4] = wv4[2*d + 1];
        float bb = out_b[d];
        float4 r = make_float4(bb, bb, bb, bb);
        #pragma unroll
        for (int o = 0; o < CD; ++o) {
            float wo = wr[o];
            r.x = fmaf(wo, qv[o].x, r.x);
            r.y = fmaf(wo, qv[o].y, r.y);
            r.z = fmaf(wo, qv[o].z, r.z);
            r.w = fmaf(wo, qv[o].w, r.w);
        }
        *(float4*)(outb + obase + (size_t)d * TT) = r;
    }
}

extern "C" void kernel_launch(void* const* d_in, const int* in_sizes, int n_in,
                              void* d_out, int out_size, void* d_ws, size_t ws_size,
                              hipStream_t stream) {
    const float* z     = (const float*)d_in[0];
    const float* in_v  = (const float*)d_in[1];
    const float* in_g  = (const float*)d_in[2];
    const float* in_b  = (const float*)d_in[3];
    const float* out_v = (const float*)d_in[4];
    const float* out_g = (const float*)d_in[5];
    const float* out_b = (const float*)d_in[6];
    const float* cb    = (const float*)d_in[7];
    float* ws  = (float*)d_ws;
    float* out = (float*)d_out;

    // zero the 32 loss accumulators (harness poisons d_out with 0xAA)
    hipMemsetAsync(out + OFF_LOSS_C, 0, 32 * sizeof(float), stream);

    prep_kernel<<<16, 256, 0, stream>>>(in_v, in_g, out_v, out_g, cb, ws);
    vq_kernel<<<dim3(TT/64, BB), 256, 0, stream>>>(z, in_b, cb, ws, out);
    out_proj_kernel<<<dim3(TT/64, BB), 256, 0, stream>>>(cb, out_b, ws, out);
}